// Round 1
// baseline (160.062 us; speedup 1.0000x reference)
//
#include <hip/hip_runtime.h>

#define BLK 256

// ---------------------------------------------------------------------------
// K1: per-voxel mask + selection + skip_features + compaction of hit voxels.
// ---------------------------------------------------------------------------
__global__ __launch_bounds__(BLK) void k1_mask_skip(
    const int* __restrict__ coords,      // [N,3]
    const int* __restrict__ batch_idx,   // [N]
    const float* __restrict__ features,  // [N,32]
    const int* __restrict__ box_batch,   // [M]
    const int* __restrict__ box_min,     // [M,3]
    const int* __restrict__ box_max,     // [M,3]
    float* __restrict__ skip_out,        // [N,32]
    float* __restrict__ sel_out,         // [N]
    int* __restrict__ cnt,
    int* __restrict__ vlist,
    unsigned long long* __restrict__ mlist,
    int N, int M, int cap)
{
    __shared__ int sbb[64], sx0[64], sy0[64], sz0[64], sx1[64], sy1[64], sz1[64];
    __shared__ float ssel[BLK];

    const int t = threadIdx.x;
    for (int m = t; m < M; m += BLK) {
        sbb[m] = box_batch[m];
        sx0[m] = box_min[m * 3 + 0];
        sy0[m] = box_min[m * 3 + 1];
        sz0[m] = box_min[m * 3 + 2];
        sx1[m] = box_max[m * 3 + 0];
        sy1[m] = box_max[m * 3 + 1];
        sz1[m] = box_max[m * 3 + 2];
    }
    __syncthreads();

    const int base = blockIdx.x * BLK;
    const int i = base + t;
    float selv = 0.0f;
    if (i < N) {
        const int x = coords[i * 3 + 0];
        const int y = coords[i * 3 + 1];
        const int z = coords[i * 3 + 2];
        const int b = batch_idx[i];
        unsigned long long mask = 0ull;
        #pragma unroll 64
        for (int m = 0; m < 64; ++m) {
            if (m < M) {
                bool ins = (sbb[m] == b)
                         & (x >= sx0[m]) & (x < sx1[m])
                         & (y >= sy0[m]) & (y < sy1[m])
                         & (z >= sz0[m]) & (z < sz1[m]);
                mask |= ((unsigned long long)ins) << m;
            }
        }
        selv = mask ? 1.0f : 0.0f;
        sel_out[i] = selv;
        if (mask) {
            int pos = atomicAdd(cnt, 1);
            if (pos < cap) {
                vlist[pos] = i;
                mlist[pos] = mask;
            }
        }
    }
    ssel[t] = selv;
    __syncthreads();

    // Cooperative, fully-coalesced skip write for this block's rows.
    const int nrows = min(BLK, N - base);
    if (nrows > 0) {
        const float4* __restrict__ f4 = (const float4*)features;
        float4* __restrict__ s4 = (float4*)skip_out;
        const int total = nrows * 8;  // 32 floats = 8 float4 per row
        for (int j = t; j < total; j += BLK) {
            const int r = j >> 3;
            const int p = j & 7;
            float4 v = f4[(size_t)(base + r) * 8 + p];
            const float sc = ssel[r];
            v.x *= sc; v.y *= sc; v.z *= sc; v.w *= sc;
            s4[(size_t)(base + r) * 8 + p] = v;
        }
    }
}

// ---------------------------------------------------------------------------
// K2: one wave per hit voxel; lanes carry channels; atomicAdd into roi[M,96].
// conv channels 0..63 from lanes 0..63, raw channels 64..95 from lanes 0..31.
// ---------------------------------------------------------------------------
__global__ __launch_bounds__(BLK) void k2_roi(
    const float* __restrict__ features,   // [N,32]
    const float* __restrict__ conv,       // [N,64]
    const int* __restrict__ cnt,
    const int* __restrict__ vlist,
    const unsigned long long* __restrict__ mlist,
    float* __restrict__ roi,              // [M,96]
    int cap)
{
    int count = *cnt;
    if (count > cap) count = cap;
    const int lane = threadIdx.x & 63;
    const int w = (blockIdx.x * blockDim.x + threadIdx.x) >> 6;
    const int nw = (gridDim.x * blockDim.x) >> 6;

    for (int v = w; v < count; v += nw) {
        const int vox = vlist[v];
        unsigned long long mask = mlist[v];
        const float cval = conv[(size_t)vox * 64 + lane];
        const float fval = (lane < 32) ? features[(size_t)vox * 32 + lane] : 0.0f;
        while (mask) {
            const int m = __ffsll((long long)mask) - 1;
            mask &= mask - 1;
            atomicAdd(&roi[m * 96 + lane], cval);
            if (lane < 32) atomicAdd(&roi[m * 96 + 64 + lane], fval);
        }
    }
}

extern "C" void kernel_launch(void* const* d_in, const int* in_sizes, int n_in,
                              void* d_out, int out_size, void* d_ws, size_t ws_size,
                              hipStream_t stream)
{
    const int* coords      = (const int*)d_in[0];
    const int* batch_idx   = (const int*)d_in[1];
    const float* features  = (const float*)d_in[2];
    const float* conv      = (const float*)d_in[3];
    const int* box_batch   = (const int*)d_in[4];
    const int* box_min     = (const int*)d_in[5];
    const int* box_max     = (const int*)d_in[6];

    const int N  = in_sizes[1];            // 500000
    const int M  = in_sizes[4];            // 64
    const int CR = in_sizes[2] / N;        // 32
    const int CC = in_sizes[3] / N;        // 64
    const int C  = CR + CC;                // 96

    float* roi  = (float*)d_out;                    // [M, C]
    float* skip = roi + (size_t)M * C;              // [N, CR]
    float* sel  = skip + (size_t)N * CR;            // [N]

    // workspace: 16B counter | vlist[cap] int | mlist[cap] u64
    size_t avail = (ws_size > 32) ? (ws_size - 32) : 0;
    size_t cap64 = avail / 12;
    if (cap64 > (size_t)N) cap64 = (size_t)N;
    cap64 &= ~(size_t)1;
    const int cap = (int)cap64;

    int* cnt = (int*)d_ws;
    int* vlist = (int*)((char*)d_ws + 16);
    unsigned long long* mlist =
        (unsigned long long*)((char*)d_ws + 16 + (((size_t)cap * 4 + 15) & ~(size_t)15));

    hipMemsetAsync(cnt, 0, 16, stream);
    hipMemsetAsync(roi, 0, (size_t)M * C * sizeof(float), stream);

    const int blocks = (N + BLK - 1) / BLK;
    k1_mask_skip<<<blocks, BLK, 0, stream>>>(coords, batch_idx, features,
                                             box_batch, box_min, box_max,
                                             skip, sel, cnt, vlist, mlist,
                                             N, M, cap);
    k2_roi<<<1024, BLK, 0, stream>>>(features, conv, cnt, vlist, mlist, roi, cap);
}

// Round 2
// 90.287 us; speedup vs baseline: 1.7728x; 1.7728x over previous
//
#include <hip/hip_runtime.h>

#define BLK 256

// ---------------------------------------------------------------------------
// K1: per-voxel mask + selection + skip_features + block-aggregated compaction.
// ---------------------------------------------------------------------------
__global__ __launch_bounds__(BLK) void k1_mask_skip(
    const int* __restrict__ coords,      // [N,3]
    const int* __restrict__ batch_idx,   // [N]
    const float* __restrict__ features,  // [N,32]
    const int* __restrict__ box_batch,   // [M]
    const int* __restrict__ box_min,     // [M,3]
    const int* __restrict__ box_max,     // [M,3]
    float* __restrict__ skip_out,        // [N,32]
    float* __restrict__ sel_out,         // [N]
    int* __restrict__ cnt,
    int* __restrict__ vlist,
    unsigned long long* __restrict__ mlist,
    int N, int M, int cap)
{
    __shared__ int4 sb0[64];             // {lo_key, hi_key, y0, y1}
    __shared__ int4 sb1[64];             // {z0, z1, -, -}
    __shared__ float ssel[BLK];
    __shared__ int wcnt[4];
    __shared__ int wbase[4];

    const int t = threadIdx.x;
    const int lane = t & 63;
    const int wid = t >> 6;

    // Stage packed box bounds. Pad m>=M with an empty range (never matches).
    if (t < 64) {
        int lo = 0x7fffffff, hi = 0, y0 = 0, y1 = 0, z0 = 0, z1 = 0;
        if (t < M) {
            const int b = box_batch[t];
            lo = (b << 9) | box_min[t * 3 + 0];
            hi = (b << 9) | box_max[t * 3 + 0];
            y0 = box_min[t * 3 + 1];  y1 = box_max[t * 3 + 1];
            z0 = box_min[t * 3 + 2];  z1 = box_max[t * 3 + 2];
        }
        sb0[t] = make_int4(lo, hi, y0, y1);
        sb1[t] = make_int4(z0, z1, 0, 0);
    }
    __syncthreads();

    const int base = blockIdx.x * BLK;
    const int i = base + t;
    unsigned long long mask = 0ull;
    if (i < N) {
        const int x = coords[i * 3 + 0];
        const int y = coords[i * 3 + 1];
        const int z = coords[i * 3 + 2];
        const int px = (batch_idx[i] << 9) | x;
        #pragma unroll 64
        for (int m = 0; m < 64; ++m) {
            const int4 q0 = sb0[m];
            const int4 q1 = sb1[m];
            const bool ins = (px >= q0.x) & (px < q0.y)
                           & (y >= q0.z) & (y < q0.w)
                           & (z >= q1.x) & (z < q1.y);
            mask |= ins ? (1ull << m) : 0ull;
        }
        sel_out[i] = mask ? 1.0f : 0.0f;
    }
    ssel[t] = mask ? 1.0f : 0.0f;

    // --- block-aggregated compaction: ONE global atomic per block ---
    const unsigned long long ball = __ballot(mask != 0ull);
    if (lane == 0) wcnt[wid] = __popcll(ball);
    __syncthreads();
    if (t == 0) {
        const int s0 = wcnt[0], s1 = wcnt[1], s2 = wcnt[2], s3 = wcnt[3];
        const int tot = s0 + s1 + s2 + s3;
        const int b = tot ? atomicAdd(cnt, tot) : 0;
        wbase[0] = b;
        wbase[1] = b + s0;
        wbase[2] = b + s0 + s1;
        wbase[3] = b + s0 + s1 + s2;
    }
    __syncthreads();
    if (mask) {
        const int pos = wbase[wid]
                      + __popcll(ball & ((1ull << lane) - 1ull));
        if (pos < cap) {
            vlist[pos] = i;
            mlist[pos] = mask;
        }
    }

    // Cooperative, fully-coalesced skip write for this block's rows.
    const int nrows = min(BLK, N - base);
    if (nrows > 0) {
        const float4* __restrict__ f4 = (const float4*)features;
        float4* __restrict__ s4 = (float4*)skip_out;
        const int total = nrows * 8;  // 32 floats = 8 float4 per row
        for (int j = t; j < total; j += BLK) {
            const int r = j >> 3;
            const int p = j & 7;
            float4 v = f4[(size_t)(base + r) * 8 + p];
            const float sc = ssel[r];
            v.x *= sc; v.y *= sc; v.z *= sc; v.w *= sc;
            s4[(size_t)(base + r) * 8 + p] = v;
        }
    }
}

// ---------------------------------------------------------------------------
// K2: one wave per hit voxel; lanes carry channels; atomicAdd into roi[M,96].
// conv channels 0..63 from lanes 0..63, raw channels 64..95 from lanes 0..31.
// ---------------------------------------------------------------------------
__global__ __launch_bounds__(BLK) void k2_roi(
    const float* __restrict__ features,   // [N,32]
    const float* __restrict__ conv,       // [N,64]
    const int* __restrict__ cnt,
    const int* __restrict__ vlist,
    const unsigned long long* __restrict__ mlist,
    float* __restrict__ roi,              // [M,96]
    int cap)
{
    int count = *cnt;
    if (count > cap) count = cap;
    const int lane = threadIdx.x & 63;
    const int w = (blockIdx.x * blockDim.x + threadIdx.x) >> 6;
    const int nw = (gridDim.x * blockDim.x) >> 6;

    for (int v = w; v < count; v += nw) {
        const int vox = vlist[v];
        unsigned long long mask = mlist[v];
        const float cval = conv[(size_t)vox * 64 + lane];
        const float fval = (lane < 32) ? features[(size_t)vox * 32 + lane] : 0.0f;
        while (mask) {
            const int m = __ffsll((long long)mask) - 1;
            mask &= mask - 1;
            atomicAdd(&roi[m * 96 + lane], cval);
            if (lane < 32) atomicAdd(&roi[m * 96 + 64 + lane], fval);
        }
    }
}

extern "C" void kernel_launch(void* const* d_in, const int* in_sizes, int n_in,
                              void* d_out, int out_size, void* d_ws, size_t ws_size,
                              hipStream_t stream)
{
    const int* coords      = (const int*)d_in[0];
    const int* batch_idx   = (const int*)d_in[1];
    const float* features  = (const float*)d_in[2];
    const float* conv      = (const float*)d_in[3];
    const int* box_batch   = (const int*)d_in[4];
    const int* box_min     = (const int*)d_in[5];
    const int* box_max     = (const int*)d_in[6];

    const int N  = in_sizes[1];            // 500000
    const int M  = in_sizes[4];            // 64
    const int CR = in_sizes[2] / N;        // 32
    const int CC = in_sizes[3] / N;        // 64
    const int C  = CR + CC;                // 96

    float* roi  = (float*)d_out;                    // [M, C]
    float* skip = roi + (size_t)M * C;              // [N, CR]
    float* sel  = skip + (size_t)N * CR;            // [N]

    // workspace: 16B counter | vlist[cap] int | mlist[cap] u64
    size_t avail = (ws_size > 32) ? (ws_size - 32) : 0;
    size_t cap64 = avail / 12;
    if (cap64 > (size_t)N) cap64 = (size_t)N;
    cap64 &= ~(size_t)1;
    const int cap = (int)cap64;

    int* cnt = (int*)d_ws;
    int* vlist = (int*)((char*)d_ws + 16);
    unsigned long long* mlist =
        (unsigned long long*)((char*)d_ws + 16 + (((size_t)cap * 4 + 15) & ~(size_t)15));

    hipMemsetAsync(cnt, 0, 16, stream);
    hipMemsetAsync(roi, 0, (size_t)M * C * sizeof(float), stream);

    const int blocks = (N + BLK - 1) / BLK;
    k1_mask_skip<<<blocks, BLK, 0, stream>>>(coords, batch_idx, features,
                                             box_batch, box_min, box_max,
                                             skip, sel, cnt, vlist, mlist,
                                             N, M, cap);
    k2_roi<<<1024, BLK, 0, stream>>>(features, conv, cnt, vlist, mlist, roi, cap);
}

// Round 3
// 82.501 us; speedup vs baseline: 1.9401x; 1.0944x over previous
//
#include <hip/hip_runtime.h>

#define BLK 256

// ---------------------------------------------------------------------------
// kA: per-voxel mask + selection + block-aggregated compaction. No streaming.
// ---------------------------------------------------------------------------
__global__ __launch_bounds__(BLK) void kA_mask(
    const int* __restrict__ coords,      // [N,3]
    const int* __restrict__ batch_idx,   // [N]
    const int* __restrict__ box_batch,   // [M]
    const int* __restrict__ box_min,     // [M,3]
    const int* __restrict__ box_max,     // [M,3]
    float* __restrict__ sel_out,         // [N]
    int* __restrict__ cnt,
    int* __restrict__ vlist,
    unsigned long long* __restrict__ mlist,
    int N, int M, int cap)
{
    __shared__ int4 sb0[64];             // {lo_key, hi_key, y0, y1}
    __shared__ int4 sb1[64];             // {z0, z1, -, -}
    __shared__ int wcnt[4];
    __shared__ int wbase[4];

    const int t = threadIdx.x;
    const int lane = t & 63;
    const int wid = t >> 6;

    // Stage packed box bounds. Pad m>=M with an empty range (never matches).
    if (t < 64) {
        int lo = 0x7fffffff, hi = 0, y0 = 0, y1 = 0, z0 = 0, z1 = 0;
        if (t < M) {
            const int b = box_batch[t];
            lo = (b << 9) | box_min[t * 3 + 0];
            hi = (b << 9) | box_max[t * 3 + 0];
            y0 = box_min[t * 3 + 1];  y1 = box_max[t * 3 + 1];
            z0 = box_min[t * 3 + 2];  z1 = box_max[t * 3 + 2];
        }
        sb0[t] = make_int4(lo, hi, y0, y1);
        sb1[t] = make_int4(z0, z1, 0, 0);
    }
    __syncthreads();

    const int i = blockIdx.x * BLK + t;
    unsigned long long mask = 0ull;
    if (i < N) {
        const int x = coords[i * 3 + 0];
        const int y = coords[i * 3 + 1];
        const int z = coords[i * 3 + 2];
        const int px = (batch_idx[i] << 9) | x;
        #pragma unroll 64
        for (int m = 0; m < 64; ++m) {
            const int4 q0 = sb0[m];
            const int4 q1 = sb1[m];
            const bool ins = (px >= q0.x) & (px < q0.y)
                           & (y >= q0.z) & (y < q0.w)
                           & (z >= q1.x) & (z < q1.y);
            mask |= ins ? (1ull << m) : 0ull;
        }
        sel_out[i] = mask ? 1.0f : 0.0f;
    }

    // --- block-aggregated compaction: ONE global atomic per block ---
    const unsigned long long ball = __ballot(mask != 0ull);
    if (lane == 0) wcnt[wid] = __popcll(ball);
    __syncthreads();
    if (t == 0) {
        const int s0 = wcnt[0], s1 = wcnt[1], s2 = wcnt[2], s3 = wcnt[3];
        const int tot = s0 + s1 + s2 + s3;
        const int b = tot ? atomicAdd(cnt, tot) : 0;
        wbase[0] = b;
        wbase[1] = b + s0;
        wbase[2] = b + s0 + s1;
        wbase[3] = b + s0 + s1 + s2;
    }
    __syncthreads();
    if (mask) {
        const int pos = wbase[wid]
                      + __popcll(ball & ((1ull << lane) - 1ull));
        if (pos < cap) {
            vlist[pos] = i;
            mlist[pos] = mask;
        }
    }
}

// ---------------------------------------------------------------------------
// k2: one wave per hit voxel; lanes carry channels; atomicAdd into roi[M,96];
//     also scatter-writes the skip row (sel==1 rows only; rest are memset 0).
// ---------------------------------------------------------------------------
__global__ __launch_bounds__(BLK) void k2_roi(
    const float* __restrict__ features,   // [N,32]
    const float* __restrict__ conv,       // [N,64]
    const int* __restrict__ cnt,
    const int* __restrict__ vlist,
    const unsigned long long* __restrict__ mlist,
    float* __restrict__ roi,              // [M,96]
    float* __restrict__ skip,             // [N,32]
    int cap)
{
    int count = *cnt;
    if (count > cap) count = cap;
    const int lane = threadIdx.x & 63;
    const int w = (blockIdx.x * blockDim.x + threadIdx.x) >> 6;
    const int nw = (gridDim.x * blockDim.x) >> 6;

    for (int v = w; v < count; v += nw) {
        const int vox = vlist[v];
        unsigned long long mask = mlist[v];
        const float cval = conv[(size_t)vox * 64 + lane];
        float fval = 0.0f;
        if (lane < 32) {
            fval = features[(size_t)vox * 32 + lane];
            skip[(size_t)vox * 32 + lane] = fval;   // sel==1 here
        }
        while (mask) {
            const int m = __ffsll((long long)mask) - 1;
            mask &= mask - 1;
            atomicAdd(&roi[m * 96 + lane], cval);
            if (lane < 32) atomicAdd(&roi[m * 96 + 64 + lane], fval);
        }
    }
}

extern "C" void kernel_launch(void* const* d_in, const int* in_sizes, int n_in,
                              void* d_out, int out_size, void* d_ws, size_t ws_size,
                              hipStream_t stream)
{
    const int* coords      = (const int*)d_in[0];
    const int* batch_idx   = (const int*)d_in[1];
    const float* features  = (const float*)d_in[2];
    const float* conv      = (const float*)d_in[3];
    const int* box_batch   = (const int*)d_in[4];
    const int* box_min     = (const int*)d_in[5];
    const int* box_max     = (const int*)d_in[6];

    const int N  = in_sizes[1];            // 500000
    const int M  = in_sizes[4];            // 64
    const int CR = in_sizes[2] / N;        // 32
    const int CC = in_sizes[3] / N;        // 64
    const int C  = CR + CC;                // 96

    float* roi  = (float*)d_out;                    // [M, C]
    float* skip = roi + (size_t)M * C;              // [N, CR]
    float* sel  = skip + (size_t)N * CR;            // [N]

    // workspace: 16B counter | vlist[cap] int | mlist[cap] u64
    size_t avail = (ws_size > 32) ? (ws_size - 32) : 0;
    size_t cap64 = avail / 12;
    if (cap64 > (size_t)N) cap64 = (size_t)N;
    cap64 &= ~(size_t)1;
    const int cap = (int)cap64;

    int* cnt = (int*)d_ws;
    int* vlist = (int*)((char*)d_ws + 16);
    unsigned long long* mlist =
        (unsigned long long*)((char*)d_ws + 16 + (((size_t)cap * 4 + 15) & ~(size_t)15));

    // Zero the skip slab (96.5% of rows stay zero) + counter + roi.
    hipMemsetAsync(skip, 0, (size_t)N * CR * sizeof(float), stream);
    hipMemsetAsync(cnt, 0, 16, stream);
    hipMemsetAsync(roi, 0, (size_t)M * C * sizeof(float), stream);

    const int blocks = (N + BLK - 1) / BLK;
    kA_mask<<<blocks, BLK, 0, stream>>>(coords, batch_idx,
                                        box_batch, box_min, box_max,
                                        sel, cnt, vlist, mlist, N, M, cap);
    k2_roi<<<1024, BLK, 0, stream>>>(features, conv, cnt, vlist, mlist,
                                     roi, skip, cap);
}

// Round 4
// 81.540 us; speedup vs baseline: 1.9630x; 1.0118x over previous
//
#include <hip/hip_runtime.h>

#define BLK 256

// ---------------------------------------------------------------------------
// kA: per-voxel mask + selection + compaction + fused skip write.
//     Selected rows (~3.5%) copy features; others write zeros (streaming).
//     Block 0 additionally zeroes roi[M*96] (k2 runs after, stream-ordered).
// ---------------------------------------------------------------------------
__global__ __launch_bounds__(BLK) void kA_mask_skip(
    const int* __restrict__ coords,      // [N,3]
    const int* __restrict__ batch_idx,   // [N]
    const float* __restrict__ features,  // [N,32]
    const int* __restrict__ box_batch,   // [M]
    const int* __restrict__ box_min,     // [M,3]
    const int* __restrict__ box_max,     // [M,3]
    float* __restrict__ skip_out,        // [N,32]
    float* __restrict__ sel_out,         // [N]
    float* __restrict__ roi,             // [M,96] -- zeroed by block 0
    int* __restrict__ cnt,
    int* __restrict__ vlist,
    unsigned long long* __restrict__ mlist,
    int N, int M, int C, int cap)
{
    __shared__ int4 sb0[64];             // {lo_key, hi_key, y0, y1}
    __shared__ int4 sb1[64];             // {z0, z1, -, -}
    __shared__ float ssel[BLK];
    __shared__ int wcnt[4];
    __shared__ int wbase[4];

    const int t = threadIdx.x;
    const int lane = t & 63;
    const int wid = t >> 6;

    if (blockIdx.x == 0) {
        const int nroi = M * C;
        for (int j = t; j < nroi; j += BLK) roi[j] = 0.0f;
    }

    // Stage packed box bounds. Pad m>=M with an empty range (never matches).
    if (t < 64) {
        int lo = 0x7fffffff, hi = 0, y0 = 0, y1 = 0, z0 = 0, z1 = 0;
        if (t < M) {
            const int b = box_batch[t];
            lo = (b << 9) | box_min[t * 3 + 0];
            hi = (b << 9) | box_max[t * 3 + 0];
            y0 = box_min[t * 3 + 1];  y1 = box_max[t * 3 + 1];
            z0 = box_min[t * 3 + 2];  z1 = box_max[t * 3 + 2];
        }
        sb0[t] = make_int4(lo, hi, y0, y1);
        sb1[t] = make_int4(z0, z1, 0, 0);
    }
    __syncthreads();

    const int base = blockIdx.x * BLK;
    const int i = base + t;
    unsigned long long mask = 0ull;
    if (i < N) {
        const int x = coords[i * 3 + 0];
        const int y = coords[i * 3 + 1];
        const int z = coords[i * 3 + 2];
        const int px = (batch_idx[i] << 9) | x;
        #pragma unroll 64
        for (int m = 0; m < 64; ++m) {
            const int4 q0 = sb0[m];
            const int4 q1 = sb1[m];
            const bool ins = (px >= q0.x) & (px < q0.y)
                           & (y >= q0.z) & (y < q0.w)
                           & (z >= q1.x) & (z < q1.y);
            mask |= ins ? (1ull << m) : 0ull;
        }
        sel_out[i] = mask ? 1.0f : 0.0f;
    }
    ssel[t] = mask ? 1.0f : 0.0f;

    // --- block-aggregated compaction: ONE global atomic per block ---
    const unsigned long long ball = __ballot(mask != 0ull);
    if (lane == 0) wcnt[wid] = __popcll(ball);
    __syncthreads();
    if (t == 0) {
        const int s0 = wcnt[0], s1 = wcnt[1], s2 = wcnt[2], s3 = wcnt[3];
        const int tot = s0 + s1 + s2 + s3;
        const int b = tot ? atomicAdd(cnt, tot) : 0;
        wbase[0] = b;
        wbase[1] = b + s0;
        wbase[2] = b + s0 + s1;
        wbase[3] = b + s0 + s1 + s2;
    }
    __syncthreads();
    if (mask) {
        const int pos = wbase[wid]
                      + __popcll(ball & ((1ull << lane) - 1ull));
        if (pos < cap) {
            vlist[pos] = i;
            mlist[pos] = mask;
        }
    }

    // Fused skip write: zeros for unselected rows, feature copy for selected.
    const int nrows = min(BLK, N - base);
    if (nrows > 0) {
        const float4* __restrict__ f4 = (const float4*)features;
        float4* __restrict__ s4 = (float4*)skip_out;
        const int total = nrows * 8;  // 32 floats = 8 float4 per row
        const float4 z4 = make_float4(0.f, 0.f, 0.f, 0.f);
        for (int j = t; j < total; j += BLK) {
            const int r = j >> 3;
            const int p = j & 7;
            const size_t idx = (size_t)(base + r) * 8 + p;
            float4 v = z4;
            if (ssel[r] != 0.0f) v = f4[idx];   // predicated load, ~3.5% of rows
            s4[idx] = v;
        }
    }
}

// ---------------------------------------------------------------------------
// k2: one wave per hit voxel; lanes carry channels; atomicAdd into roi[M,96].
// conv channels 0..63 from lanes 0..63, raw channels 64..95 from lanes 0..31.
// ---------------------------------------------------------------------------
__global__ __launch_bounds__(BLK) void k2_roi(
    const float* __restrict__ features,   // [N,32]
    const float* __restrict__ conv,       // [N,64]
    const int* __restrict__ cnt,
    const int* __restrict__ vlist,
    const unsigned long long* __restrict__ mlist,
    float* __restrict__ roi,              // [M,96]
    int cap)
{
    int count = *cnt;
    if (count > cap) count = cap;
    const int lane = threadIdx.x & 63;
    const int w = (blockIdx.x * blockDim.x + threadIdx.x) >> 6;
    const int nw = (gridDim.x * blockDim.x) >> 6;

    for (int v = w; v < count; v += nw) {
        const int vox = vlist[v];
        unsigned long long mask = mlist[v];
        const float cval = conv[(size_t)vox * 64 + lane];
        const float fval = (lane < 32) ? features[(size_t)vox * 32 + lane] : 0.0f;
        while (mask) {
            const int m = __ffsll((long long)mask) - 1;
            mask &= mask - 1;
            atomicAdd(&roi[m * 96 + lane], cval);
            if (lane < 32) atomicAdd(&roi[m * 96 + 64 + lane], fval);
        }
    }
}

extern "C" void kernel_launch(void* const* d_in, const int* in_sizes, int n_in,
                              void* d_out, int out_size, void* d_ws, size_t ws_size,
                              hipStream_t stream)
{
    const int* coords      = (const int*)d_in[0];
    const int* batch_idx   = (const int*)d_in[1];
    const float* features  = (const float*)d_in[2];
    const float* conv      = (const float*)d_in[3];
    const int* box_batch   = (const int*)d_in[4];
    const int* box_min     = (const int*)d_in[5];
    const int* box_max     = (const int*)d_in[6];

    const int N  = in_sizes[1];            // 500000
    const int M  = in_sizes[4];            // 64
    const int CR = in_sizes[2] / N;        // 32
    const int CC = in_sizes[3] / N;        // 64
    const int C  = CR + CC;                // 96

    float* roi  = (float*)d_out;                    // [M, C]
    float* skip = roi + (size_t)M * C;              // [N, CR]
    float* sel  = skip + (size_t)N * CR;            // [N]

    // workspace: 16B counter | vlist[cap] int | mlist[cap] u64
    size_t avail = (ws_size > 32) ? (ws_size - 32) : 0;
    size_t cap64 = avail / 12;
    if (cap64 > (size_t)N) cap64 = (size_t)N;
    cap64 &= ~(size_t)1;
    const int cap = (int)cap64;

    int* cnt = (int*)d_ws;
    int* vlist = (int*)((char*)d_ws + 16);
    unsigned long long* mlist =
        (unsigned long long*)((char*)d_ws + 16 + (((size_t)cap * 4 + 15) & ~(size_t)15));

    hipMemsetAsync(cnt, 0, 16, stream);   // only remaining fill (16 B)

    const int blocks = (N + BLK - 1) / BLK;
    kA_mask_skip<<<blocks, BLK, 0, stream>>>(coords, batch_idx, features,
                                             box_batch, box_min, box_max,
                                             skip, sel, roi, cnt, vlist, mlist,
                                             N, M, C, cap);
    k2_roi<<<1024, BLK, 0, stream>>>(features, conv, cnt, vlist, mlist,
                                     roi, cap);
}

// Round 5
// 69.583 us; speedup vs baseline: 2.3003x; 1.1718x over previous
//
#include <hip/hip_runtime.h>

#define BLK 256
#define VPT 4
#define RB (BLK * VPT)   // 1024 rows per block == one compaction region

// ---------------------------------------------------------------------------
// kA: mask (4 voxels/thread), selection, per-region compaction (no atomics,
//     no memsets), fused skip write. Block 0 zeroes roi[M*C].
// ---------------------------------------------------------------------------
__global__ __launch_bounds__(BLK) void kA_mask_skip(
    const int* __restrict__ coords,      // [N,3]
    const int* __restrict__ batch_idx,   // [N]
    const float* __restrict__ features,  // [N,32]
    const int* __restrict__ box_batch,   // [M]
    const int* __restrict__ box_min,     // [M,3]
    const int* __restrict__ box_max,     // [M,3]
    float* __restrict__ skip_out,        // [N,32]
    float* __restrict__ sel_out,         // [N]
    float* __restrict__ roi,             // [M,C] zeroed here by block 0
    int* __restrict__ vcnt,              // [nreg]
    int* __restrict__ vlist,             // [nreg*RB]
    unsigned long long* __restrict__ mlist, // [nreg*RB]
    int N, int M, int C)
{
    __shared__ int4 sb0[64];             // {lo_key, hi_key, y0, y1}
    __shared__ int4 sb1[64];             // {z0, z1, -, -}
    __shared__ float ssel[RB];
    __shared__ int wc[16];
    __shared__ int wb[16];

    const int t = threadIdx.x;
    const int lane = t & 63;
    const int wid = t >> 6;
    const int base = blockIdx.x * RB;

    if (blockIdx.x == 0) {
        const int nroi = M * C;
        for (int j = t; j < nroi; j += BLK) roi[j] = 0.0f;
    }

    // Stage packed box bounds; pad m>=M with an empty range.
    if (t < 64) {
        int lo = 0x7fffffff, hi = -1, y0 = 0, y1 = 0, z0 = 0, z1 = 0;
        if (t < M) {
            const int b = box_batch[t];
            lo = (b << 9) | box_min[t * 3 + 0];
            hi = (b << 9) | box_max[t * 3 + 0];
            y0 = box_min[t * 3 + 1];  y1 = box_max[t * 3 + 1];
            z0 = box_min[t * 3 + 2];  z1 = box_max[t * 3 + 2];
        }
        sb0[t] = make_int4(lo, hi, y0, y1);
        sb1[t] = make_int4(z0, z1, 0, 0);
    }
    __syncthreads();

    // ---- mask: 4 voxels per thread, box data read once per 4 tests ----
    int px[VPT], py[VPT], pz[VPT];
    unsigned long long mask[VPT];
    #pragma unroll
    for (int v = 0; v < VPT; ++v) {
        const int i = base + v * BLK + t;
        mask[v] = 0ull;
        if (i < N) {
            const int x = coords[(size_t)i * 3 + 0];
            const int y = coords[(size_t)i * 3 + 1];
            const int z = coords[(size_t)i * 3 + 2];
            px[v] = (batch_idx[i] << 9) | x;
            py[v] = y;  pz[v] = z;
        } else {
            px[v] = -1;  py[v] = -1;  pz[v] = -1;   // never inside any box
        }
    }
    #pragma unroll 8
    for (int m = 0; m < 64; ++m) {
        const int4 q0 = sb0[m];
        const int4 q1 = sb1[m];
        #pragma unroll
        for (int v = 0; v < VPT; ++v) {
            const bool ins = (px[v] >= q0.x) & (px[v] < q0.y)
                           & (py[v] >= q0.z) & (py[v] < q0.w)
                           & (pz[v] >= q1.x) & (pz[v] < q1.y);
            mask[v] |= ins ? (1ull << m) : 0ull;
        }
    }

    // selection output + LDS flags for the skip pass
    #pragma unroll
    for (int v = 0; v < VPT; ++v) {
        const int i = base + v * BLK + t;
        const float s = mask[v] ? 1.0f : 0.0f;
        ssel[v * BLK + t] = s;
        if (i < N) sel_out[i] = s;
    }

    // ---- deterministic per-region compaction (no global atomics) ----
    unsigned long long ball[VPT];
    #pragma unroll
    for (int v = 0; v < VPT; ++v) ball[v] = __ballot(mask[v] != 0ull);
    if (lane == 0) {
        #pragma unroll
        for (int v = 0; v < VPT; ++v) wc[wid * VPT + v] = __popcll(ball[v]);
    }
    __syncthreads();
    if (t == 0) {
        int s = 0;
        #pragma unroll
        for (int k = 0; k < 16; ++k) { wb[k] = s; s += wc[k]; }
        vcnt[blockIdx.x] = s;
    }
    __syncthreads();
    #pragma unroll
    for (int v = 0; v < VPT; ++v) {
        if (mask[v]) {
            const int pos = base + wb[wid * VPT + v]
                          + __popcll(ball[v] & ((1ull << lane) - 1ull));
            vlist[pos] = base + v * BLK + t;
            mlist[pos] = mask[v];
        }
    }

    // ---- fused skip write: zeros except selected rows (~3.5%) ----
    const int nrows = min(RB, N - base);
    if (nrows > 0) {
        const float4* __restrict__ f4 = (const float4*)features;
        float4* __restrict__ s4 = (float4*)skip_out;
        const int total = nrows * 8;  // 8 float4 per 32-float row
        const float4 z4 = make_float4(0.f, 0.f, 0.f, 0.f);
        for (int j = t; j < total; j += BLK) {
            const int r = j >> 3;
            const int p = j & 7;
            const size_t idx = (size_t)(base + r) * 8 + p;
            float4 vv = z4;
            if (ssel[r] != 0.0f) vv = f4[idx];
            s4[idx] = vv;
        }
    }
}

// ---------------------------------------------------------------------------
// k2: one block per region; 4 waves split the region's compacted entries.
//     Lanes carry channels; atomicAdd into roi[M,96].
// ---------------------------------------------------------------------------
__global__ __launch_bounds__(BLK) void k2_roi(
    const float* __restrict__ features,   // [N,32]
    const float* __restrict__ conv,       // [N,64]
    const int* __restrict__ vcnt,
    const int* __restrict__ vlist,
    const unsigned long long* __restrict__ mlist,
    float* __restrict__ roi,              // [M,96]
    int nreg)
{
    const int lane = threadIdx.x & 63;
    const int wid = threadIdx.x >> 6;
    const int r = blockIdx.x;
    if (r >= nreg) return;
    const int c = vcnt[r];
    const int rb = r * RB;

    for (int j = wid; j < c; j += 4) {
        const int vox = vlist[rb + j];
        unsigned long long mask = mlist[rb + j];
        const float cval = conv[(size_t)vox * 64 + lane];
        const float fval = (lane < 32) ? features[(size_t)vox * 32 + lane] : 0.0f;
        while (mask) {
            const int m = __ffsll((long long)mask) - 1;
            mask &= mask - 1;
            atomicAdd(&roi[m * 96 + lane], cval);
            if (lane < 32) atomicAdd(&roi[m * 96 + 64 + lane], fval);
        }
    }
}

extern "C" void kernel_launch(void* const* d_in, const int* in_sizes, int n_in,
                              void* d_out, int out_size, void* d_ws, size_t ws_size,
                              hipStream_t stream)
{
    const int* coords      = (const int*)d_in[0];
    const int* batch_idx   = (const int*)d_in[1];
    const float* features  = (const float*)d_in[2];
    const float* conv      = (const float*)d_in[3];
    const int* box_batch   = (const int*)d_in[4];
    const int* box_min     = (const int*)d_in[5];
    const int* box_max     = (const int*)d_in[6];

    const int N  = in_sizes[1];            // 500000
    const int M  = in_sizes[4];            // 64
    const int CR = in_sizes[2] / N;        // 32
    const int CC = in_sizes[3] / N;        // 64
    const int C  = CR + CC;                // 96

    float* roi  = (float*)d_out;                    // [M, C]
    float* skip = roi + (size_t)M * C;              // [N, CR]
    float* sel  = skip + (size_t)N * CR;            // [N]

    const int nreg = (N + RB - 1) / RB;             // 489 regions

    // workspace: vcnt[nreg] | vlist[nreg*RB] | mlist[nreg*RB]  (~6 MB)
    int* vcnt = (int*)d_ws;
    int* vlist = (int*)((char*)d_ws + (((size_t)nreg * 4 + 255) & ~(size_t)255));
    unsigned long long* mlist =
        (unsigned long long*)((char*)vlist + (((size_t)nreg * RB * 4 + 255) & ~(size_t)255));

    kA_mask_skip<<<nreg, BLK, 0, stream>>>(coords, batch_idx, features,
                                           box_batch, box_min, box_max,
                                           skip, sel, roi, vcnt, vlist, mlist,
                                           N, M, C);
    k2_roi<<<nreg, BLK, 0, stream>>>(features, conv, vcnt, vlist, mlist,
                                     roi, nreg);
}

// Round 6
// 65.504 us; speedup vs baseline: 2.4435x; 1.0623x over previous
//
#include <hip/hip_runtime.h>

#define BLK 256
#define VPT 4
#define RB (BLK * VPT)   // 1024 rows per block

typedef float v4f __attribute__((ext_vector_type(4)));

// ---------------------------------------------------------------------------
// k0: zero roi[M*C] (24 KB) so kA can atomically accumulate into d_out.
// ---------------------------------------------------------------------------
__global__ __launch_bounds__(BLK) void k0_zero_roi(float* __restrict__ roi, int n)
{
    const int t = blockIdx.x * BLK + threadIdx.x;
    if (t < n) roi[t] = 0.0f;
}

// ---------------------------------------------------------------------------
// kA: fully fused. Per region of 1024 rows:
//   1) mask 4 voxels/thread against 64 LDS-staged boxes
//   2) sel write (nt) + block-local LDS compaction of hit voxels
//   3) ROI phase: 4 waves gather conv/feature rows of hits, atomicAdd to roi
//   4) skip write (nt): zeros except selected rows (~3.5% copy features)
// ---------------------------------------------------------------------------
__global__ __launch_bounds__(BLK) void kA_fused(
    const int* __restrict__ coords,      // [N,3]
    const int* __restrict__ batch_idx,   // [N]
    const float* __restrict__ features,  // [N,32]
    const float* __restrict__ conv,      // [N,64]
    const int* __restrict__ box_batch,   // [M]
    const int* __restrict__ box_min,     // [M,3]
    const int* __restrict__ box_max,     // [M,3]
    float* __restrict__ skip_out,        // [N,32]
    float* __restrict__ sel_out,         // [N]
    float* __restrict__ roi,             // [M,96] pre-zeroed by k0
    int N, int M)
{
    __shared__ int4 sb0[64];             // {lo_key, hi_key, y0, y1}
    __shared__ int4 sb1[64];             // {z0, z1, -, -}
    __shared__ float ssel[RB];
    __shared__ int svox[RB];
    __shared__ unsigned long long smask[RB];
    __shared__ int wc[16];
    __shared__ int wb[16];
    __shared__ int scnt;

    const int t = threadIdx.x;
    const int lane = t & 63;
    const int wid = t >> 6;
    const int base = blockIdx.x * RB;

    // Stage packed box bounds; pad m>=M with an empty range.
    if (t < 64) {
        int lo = 0x7fffffff, hi = -1, y0 = 0, y1 = 0, z0 = 0, z1 = 0;
        if (t < M) {
            const int b = box_batch[t];
            lo = (b << 9) | box_min[t * 3 + 0];
            hi = (b << 9) | box_max[t * 3 + 0];
            y0 = box_min[t * 3 + 1];  y1 = box_max[t * 3 + 1];
            z0 = box_min[t * 3 + 2];  z1 = box_max[t * 3 + 2];
        }
        sb0[t] = make_int4(lo, hi, y0, y1);
        sb1[t] = make_int4(z0, z1, 0, 0);
    }
    __syncthreads();

    // ---- mask: 4 voxels per thread ----
    int px[VPT], py[VPT], pz[VPT];
    unsigned long long mask[VPT];
    #pragma unroll
    for (int v = 0; v < VPT; ++v) {
        const int i = base + v * BLK + t;
        mask[v] = 0ull;
        if (i < N) {
            const int x = coords[(size_t)i * 3 + 0];
            const int y = coords[(size_t)i * 3 + 1];
            const int z = coords[(size_t)i * 3 + 2];
            px[v] = (batch_idx[i] << 9) | x;
            py[v] = y;  pz[v] = z;
        } else {
            px[v] = -1;  py[v] = -1;  pz[v] = -1;
        }
    }
    #pragma unroll 8
    for (int m = 0; m < 64; ++m) {
        const int4 q0 = sb0[m];
        const int4 q1 = sb1[m];
        #pragma unroll
        for (int v = 0; v < VPT; ++v) {
            const bool ins = (px[v] >= q0.x) & (px[v] < q0.y)
                           & (py[v] >= q0.z) & (py[v] < q0.w)
                           & (pz[v] >= q1.x) & (pz[v] < q1.y);
            mask[v] |= ins ? (1ull << m) : 0ull;
        }
    }

    // selection output (nt) + LDS flags
    #pragma unroll
    for (int v = 0; v < VPT; ++v) {
        const int i = base + v * BLK + t;
        const float s = mask[v] ? 1.0f : 0.0f;
        ssel[v * BLK + t] = s;
        if (i < N) __builtin_nontemporal_store(s, &sel_out[i]);
    }

    // ---- block-local compaction into LDS (deterministic, no atomics) ----
    unsigned long long ball[VPT];
    #pragma unroll
    for (int v = 0; v < VPT; ++v) ball[v] = __ballot(mask[v] != 0ull);
    if (lane == 0) {
        #pragma unroll
        for (int v = 0; v < VPT; ++v) wc[wid * VPT + v] = __popcll(ball[v]);
    }
    __syncthreads();
    if (t == 0) {
        int s = 0;
        #pragma unroll
        for (int k = 0; k < 16; ++k) { wb[k] = s; s += wc[k]; }
        scnt = s;
    }
    __syncthreads();
    #pragma unroll
    for (int v = 0; v < VPT; ++v) {
        if (mask[v]) {
            const int pos = wb[wid * VPT + v]
                          + __popcll(ball[v] & ((1ull << lane) - 1ull));
            svox[pos] = base + v * BLK + t;
            smask[pos] = mask[v];
        }
    }
    __syncthreads();

    // ---- ROI phase: 4 waves split this block's hits ----
    const int cnt = scnt;
    for (int j = wid; j < cnt; j += 4) {
        const int vox = svox[j];
        unsigned long long mk = smask[j];
        const float cval = conv[(size_t)vox * 64 + lane];
        const float fval = (lane < 32) ? features[(size_t)vox * 32 + lane] : 0.0f;
        while (mk) {
            const int m = __ffsll((long long)mk) - 1;
            mk &= mk - 1;
            atomicAdd(&roi[m * 96 + lane], cval);
            if (lane < 32) atomicAdd(&roi[m * 96 + 64 + lane], fval);
        }
    }

    // ---- skip write (nt): zeros except selected rows ----
    const int nrows = min(RB, N - base);
    if (nrows > 0) {
        const v4f* __restrict__ f4 = (const v4f*)features;
        v4f* __restrict__ s4 = (v4f*)skip_out;
        const int total = nrows * 8;           // 8 float4 per 32-float row
        for (int j = t; j < total; j += BLK) {
            const int r = j >> 3;
            const size_t idx = (size_t)base * 8 + j;
            v4f vv = {0.f, 0.f, 0.f, 0.f};
            if (ssel[r] != 0.0f) vv = f4[idx];
            __builtin_nontemporal_store(vv, &s4[idx]);
        }
    }
}

extern "C" void kernel_launch(void* const* d_in, const int* in_sizes, int n_in,
                              void* d_out, int out_size, void* d_ws, size_t ws_size,
                              hipStream_t stream)
{
    const int* coords      = (const int*)d_in[0];
    const int* batch_idx   = (const int*)d_in[1];
    const float* features  = (const float*)d_in[2];
    const float* conv      = (const float*)d_in[3];
    const int* box_batch   = (const int*)d_in[4];
    const int* box_min     = (const int*)d_in[5];
    const int* box_max     = (const int*)d_in[6];

    const int N  = in_sizes[1];            // 500000
    const int M  = in_sizes[4];            // 64
    const int CR = in_sizes[2] / N;        // 32
    const int CC = in_sizes[3] / N;        // 64
    const int C  = CR + CC;                // 96

    float* roi  = (float*)d_out;                    // [M, C]
    float* skip = roi + (size_t)M * C;              // [N, CR]
    float* sel  = skip + (size_t)N * CR;            // [N]

    const int nroi = M * C;                         // 6144
    const int nreg = (N + RB - 1) / RB;             // 489

    k0_zero_roi<<<(nroi + BLK - 1) / BLK, BLK, 0, stream>>>(roi, nroi);
    kA_fused<<<nreg, BLK, 0, stream>>>(coords, batch_idx, features, conv,
                                       box_batch, box_min, box_max,
                                       skip, sel, roi, N, M);
}